// Round 3
// baseline (246939.429 us; speedup 1.0000x reference)
//
#include <hip/hip_runtime.h>
#include <cstdint>
#include <cstddef>
#include <math.h>

#define A_N   1024
#define OBS_N 2048
#define TD_N  256
#define H_N   128
#define M_N   16
#define AE_N  64
#define NWG   256

__device__ __forceinline__ float sigf(float x) { return 1.0f / (1.0f + expf(-x)); }

// C may arrive as uint8 (1B/elem) or int32 (4B/elem). Detect on device.
__device__ __forceinline__ bool c_at(const unsigned char* C, int as_int, size_t idx) {
  return as_int ? (((const int*)C)[idx] != 0) : (C[idx] != 0);
}

// ---------------- k_cdet: detect C element width ----------------
// First 4096 bytes: uint8 layout covers rows 0-3 -> 64 nonzero bytes;
// int32 layout covers row 0 -> 16 nonzero bytes.
__global__ __launch_bounds__(64) void k_cdet(const unsigned char* __restrict__ C, int* __restrict__ flag) {
  int lane = threadIdx.x;
  int cnt = 0;
  for (int i = lane; i < 4096; i += 64) cnt += (C[i] != 0) ? 1 : 0;
  for (int off = 32; off; off >>= 1) cnt += __shfl_down(cnt, off);
  if (lane == 0) flag[0] = (cnt < 40) ? 1 : 0;
}

// ---------------- k1: t = relu(LN(obs@W1 + b1)) ----------------
__global__ __launch_bounds__(256) void k_actor1a(const float* __restrict__ obs,
    const float* __restrict__ W1, const float* __restrict__ b1,
    const float* __restrict__ g1, const float* __restrict__ bt1,
    float* __restrict__ tout) {
  __shared__ float S[4 * OBS_N];
  __shared__ float red[4][4][2];
  int tid = threadIdx.x;
  int r0 = blockIdx.x * 4;
  {
    const float4* src = (const float4*)(obs + (size_t)r0 * OBS_N);
    float4* dst = (float4*)S;
    for (int i = tid; i < 4 * OBS_N / 4; i += 256) dst[i] = src[i];
  }
  __syncthreads();
  int j = tid;
  float acc0 = 0, acc1 = 0, acc2 = 0, acc3 = 0;
  const float4* S4 = (const float4*)S;
  for (int k4 = 0; k4 < OBS_N / 4; k4++) {
    float w0 = W1[(k4 * 4 + 0) * TD_N + j];
    float w1 = W1[(k4 * 4 + 1) * TD_N + j];
    float w2 = W1[(k4 * 4 + 2) * TD_N + j];
    float w3 = W1[(k4 * 4 + 3) * TD_N + j];
    float4 s0 = S4[0 * 512 + k4], s1 = S4[1 * 512 + k4], s2 = S4[2 * 512 + k4], s3 = S4[3 * 512 + k4];
    acc0 += s0.x * w0 + s0.y * w1 + s0.z * w2 + s0.w * w3;
    acc1 += s1.x * w0 + s1.y * w1 + s1.z * w2 + s1.w * w3;
    acc2 += s2.x * w0 + s2.y * w1 + s2.z * w2 + s2.w * w3;
    acc3 += s3.x * w0 + s3.y * w1 + s3.z * w2 + s3.w * w3;
  }
  float z[4] = {acc0 + b1[j], acc1 + b1[j], acc2 + b1[j], acc3 + b1[j]};
  int w = tid >> 6, lane = tid & 63;
  for (int r = 0; r < 4; r++) {
    float v = z[r], v2 = z[r] * z[r];
    for (int off = 32; off; off >>= 1) { v += __shfl_down(v, off); v2 += __shfl_down(v2, off); }
    if (lane == 0) { red[r][w][0] = v; red[r][w][1] = v2; }
  }
  __syncthreads();
  for (int r = 0; r < 4; r++) {
    float sm = red[r][0][0] + red[r][1][0] + red[r][2][0] + red[r][3][0];
    float sq = red[r][0][1] + red[r][1][1] + red[r][2][1] + red[r][3][1];
    float mean = sm * (1.0f / TD_N);
    float var = sq * (1.0f / TD_N) - mean * mean;
    float rs = 1.0f / sqrtf(var + 1e-5f);
    float val = (z[r] - mean) * rs * g1[j] + bt1[j];
    tout[(size_t)(r0 + r) * TD_N + j] = fmaxf(val, 0.0f);
  }
}

// ---------------- k2: thoughts = LN(t@W2 + b2) -> writes th (= d_out) ----------------
__global__ __launch_bounds__(256) void k_actor1b(const float* __restrict__ tin,
    const float* __restrict__ W2, const float* __restrict__ b2,
    const float* __restrict__ g2, const float* __restrict__ bt2,
    float* __restrict__ th) {
  __shared__ float S[4 * TD_N];
  __shared__ float red[4][4][2];
  int tid = threadIdx.x;
  int r0 = blockIdx.x * 4;
  for (int i = tid; i < 4 * TD_N; i += 256) S[i] = tin[(size_t)r0 * TD_N + i];
  __syncthreads();
  int j = tid;
  float z[4] = {0, 0, 0, 0};
  const float4* S4 = (const float4*)S;
  for (int k4 = 0; k4 < TD_N / 4; k4++) {
    float w0 = W2[(k4 * 4 + 0) * TD_N + j];
    float w1 = W2[(k4 * 4 + 1) * TD_N + j];
    float w2v = W2[(k4 * 4 + 2) * TD_N + j];
    float w3 = W2[(k4 * 4 + 3) * TD_N + j];
#pragma unroll
    for (int r = 0; r < 4; r++) {
      float4 sv = S4[r * 64 + k4];
      z[r] += sv.x * w0 + sv.y * w1 + sv.z * w2v + sv.w * w3;
    }
  }
  for (int r = 0; r < 4; r++) z[r] += b2[j];
  int w = tid >> 6, lane = tid & 63;
  for (int r = 0; r < 4; r++) {
    float v = z[r], v2 = z[r] * z[r];
    for (int off = 32; off; off >>= 1) { v += __shfl_down(v, off); v2 += __shfl_down(v2, off); }
    if (lane == 0) { red[r][w][0] = v; red[r][w][1] = v2; }
  }
  __syncthreads();
  for (int r = 0; r < 4; r++) {
    float sm = red[r][0][0] + red[r][1][0] + red[r][2][0] + red[r][3][0];
    float sq = red[r][0][1] + red[r][1][1] + red[r][2][1] + red[r][3][1];
    float mean = sm * (1.0f / TD_N);
    float var = sq * (1.0f / TD_N) - mean * mean;
    float rs = 1.0f / sqrtf(var + 1e-5f);
    th[(size_t)(r0 + r) * TD_N + j] = (z[r] - mean) * rs * g2[j] + bt2[j];
  }
}

// ---------------- k3: attention unit -> is_init (fp64: x>0 decision is razor-thin) ----------------
__global__ __launch_bounds__(256) void k_att(const float* __restrict__ th,
    const float* __restrict__ aW1, const float* __restrict__ ab1,
    const float* __restrict__ aW2, const float* __restrict__ ab2,
    const float* __restrict__ aW3, const float* __restrict__ ab3,
    int* __restrict__ isin) {
  __shared__ float S[4 * TD_N];
  __shared__ double A1[4 * AE_N];
  __shared__ double A2[4 * AE_N];
  int tid = threadIdx.x;
  int r0 = blockIdx.x * 4;
  for (int i = tid; i < 4 * TD_N; i += 256) S[i] = th[(size_t)r0 * TD_N + i];
  __syncthreads();
  int r = tid >> 6, c = tid & 63;
  double acc = 0;
  for (int k = 0; k < TD_N; k++) acc += (double)S[r * TD_N + k] * (double)aW1[k * AE_N + c];
  acc += (double)ab1[c];
  A1[r * AE_N + c] = acc > 0.0 ? acc : 0.0;
  __syncthreads();
  acc = 0;
  for (int k = 0; k < AE_N; k++) acc += A1[r * AE_N + k] * (double)aW2[k * AE_N + c];
  acc += (double)ab2[c];
  A2[r * AE_N + c] = acc > 0.0 ? acc : 0.0;
  __syncthreads();
  double p = A2[r * AE_N + c] * (double)aW3[c];
  for (int off = 32; off; off >>= 1) p += __shfl_down(p, off);
  if (c == 0) isin[r0 + r] = ((p + (double)ab3[0]) > 0.0) ? 1 : 0;
}

// ---------------- k_memb: member indices (ascending) per row ----------------
__global__ __launch_bounds__(64) void k_memb(const unsigned char* __restrict__ C,
    const int* __restrict__ flag, int* __restrict__ memb) {
  int s = blockIdx.x, lane = threadIdx.x;
  int as_int = flag[0];
  if (lane < M_N) memb[s * M_N + lane] = lane;  // safe defaults (never poison)
  __syncthreads();
  int base = 0;
  for (int ch = 0; ch < 16; ch++) {
    int col = ch * 64 + lane;
    bool v = c_at(C, as_int, (size_t)s * A_N + col);
    unsigned long long m = __ballot(v);
    if (v) {
      int pos = base + __popcll(m & ((1ull << lane) - 1ull));
      if (pos < M_N) memb[s * M_N + pos] = col;
    }
    base += __popcll(m);
  }
}

// ---------------- k_req: required version per (step, member slot) ----------------
__global__ __launch_bounds__(256) void k_req(const unsigned char* __restrict__ C,
    const int* __restrict__ flag, const int* __restrict__ memb,
    const int* __restrict__ isin, int* __restrict__ req) {
  __shared__ int Ls[A_N];
  int s = blockIdx.x, tid = threadIdx.x;
  int as_int = flag[0];
  for (int i = tid; i < A_N; i += 256) Ls[i] = isin[i];
  __syncthreads();
  int i = tid >> 4, sub = tid & 15;
  int m = memb[s * M_N + i] & (A_N - 1);
  int cnt = 0;
  for (int s2 = sub; s2 < s; s2 += 16)
    if (Ls[s2] && c_at(C, as_int, (size_t)s2 * A_N + m)) cnt++;
  for (int off = 1; off < 16; off <<= 1) cnt += __shfl_xor(cnt, off);
  if (sub == 0) req[s * M_N + i] = cnt;
}

// ---------------- k_prep: k-major weight re-layouts, bias sums, ver reset ----------------
__global__ __launch_bounds__(256) void k_prep(
    const float* __restrict__ Wih_f, const float* __restrict__ Wih_r,
    const float* __restrict__ Whh_f, const float* __restrict__ Whh_r,
    const float* __restrict__ bih_f, const float* __restrict__ bhh_f,
    const float* __restrict__ bih_r, const float* __restrict__ bhh_r,
    float* __restrict__ Wih4f, float* __restrict__ Wih4r,
    float* __restrict__ Whh4f, float* __restrict__ Whh4r,
    float* __restrict__ bsumf, float* __restrict__ bsumr, int* __restrict__ ver) {
  int id = blockIdx.x * 256 + threadIdx.x;  // 512*256 = 131072
  {
    // Wih4[(k4*512+g)*4+kk] = Wih[g*256 + k4*4 + kk], k4 in [0,64)
    int kk = id & 3, g = (id >> 2) & 511, k4 = id >> 11;
    Wih4f[id] = Wih_f[g * TD_N + k4 * 4 + kk];
    Wih4r[id] = Wih_r[g * TD_N + k4 * 4 + kk];
  }
  if (id < 65536) {
    // Whh4[(k4*512+g)*4+kk] = Whh[g*128 + k4*4 + kk], k4 in [0,32)
    int kk = id & 3, g = (id >> 2) & 511, k4 = id >> 11;
    Whh4f[id] = Whh_f[g * H_N + k4 * 4 + kk];
    Whh4r[id] = Whh_r[g * H_N + k4 * 4 + kk];
  }
  if (id < 512) { bsumf[id] = bih_f[id] + bhh_f[id]; bsumr[id] = bih_r[id] + bhh_r[id]; }
  if (id < A_N) ver[id] = 0;
}

// ---------------- k_comm: persistent dataflow scan ----------------
// Static LDS ~20.5 KB; 512 threads (8 waves) -> 4 WG/CU capacity, grid = 256
// on 256 CUs: all WGs co-resident -> version-wait protocol cannot deadlock.
__global__ __launch_bounds__(512) void k_comm(float* __restrict__ thoughts,
    const int* __restrict__ memb, const int* __restrict__ req,
    const int* __restrict__ isin, int* __restrict__ ver,
    const float* __restrict__ Wih4f, const float* __restrict__ Wih4r,
    const float* __restrict__ Whh4f, const float* __restrict__ Whh4r,
    const float* __restrict__ bsumf, const float* __restrict__ bsumr) {
  __shared__ float S[16 * TD_N];        // 16 KB
  __shared__ float hb[2 * 2 * H_N];     // [dir][buf][128] 2 KB
  __shared__ float gFb[2 * H_N];        // 1 KB
  __shared__ float gOb[2 * H_N];        // 1 KB
  __shared__ int memb_s[16];
  int tid = threadIdx.x;
  int dir = tid >> 8, g1 = tid & 255;
  int dmask = dir ? 15 : 0;
  const float* Wih4 = dir ? Wih4r : Wih4f;
  const float* W4   = dir ? Whh4r : Whh4f;
  const float* bsum = dir ? bsumr : bsumf;

  for (int s = blockIdx.x; s < A_N; s += NWG) {
    if (!isin[s]) continue;  // inactive step: exact no-op in reference
    if (tid < 16) memb_s[tid] = memb[s * M_N + tid] & (A_N - 1);
    __syncthreads();
    if (tid < 16) {
      int m = memb_s[tid], rq = req[s * M_N + tid];
      int tries = 0;
      while (__hip_atomic_load(&ver[m], __ATOMIC_ACQUIRE, __HIP_MEMORY_SCOPE_AGENT) < rq) {
        __builtin_amdgcn_s_sleep(8);
        if (++tries > (1 << 22)) break;  // failsafe: absmax-fail beats a hang
      }
    }
    __syncthreads();
    {  // gather 16 member rows into LDS
      int r = tid >> 5, p = tid & 31;
      const float4* src = (const float4*)(thoughts + (size_t)memb_s[r] * TD_N + p * 8);
      float4* dst = (float4*)(S + r * TD_N + p * 8);
      dst[0] = src[0]; dst[1] = src[1];
    }
    __syncthreads();
    // ---- input transform into registers: xlo[t]=X[dir][t][g1], xhi[t]=X[dir][t][g1+256]
    float xlo[16], xhi[16];
    {
      float blo = bsum[g1], bhi = bsum[g1 + 256];
#pragma unroll
      for (int t = 0; t < 16; t++) { xlo[t] = blo; xhi[t] = bhi; }
      const float4* S4 = (const float4*)S;
      for (int k4 = 0; k4 < 64; k4++) {
        float4 wlo = *(const float4*)(Wih4 + (size_t)(k4 * 512 + g1) * 4);
        float4 whi = *(const float4*)(Wih4 + (size_t)(k4 * 512 + g1 + 256) * 4);
#pragma unroll
        for (int t = 0; t < 16; t++) {
          float4 sv = S4[(t ^ dmask) * 64 + k4];   // dir=1 reads reversed sequence (15-t == t^15)
          xlo[t] += sv.x * wlo.x + sv.y * wlo.y + sv.z * wlo.z + sv.w * wlo.w;
          xhi[t] += sv.x * whi.x + sv.y * whi.y + sv.z * whi.z + sv.w * whi.w;
        }
      }
    }
    // ---- recurrence: thread owns gates g1 (i or f) and g1+256 (g or o) of its dir
    if (g1 < H_N) hb[dir * 256 + g1] = 0.0f;  // h0 = 0 in buf 0
    __syncthreads();
    float c = 0.0f;
    int buf = 0;
#pragma unroll
    for (int u = 0; u < 16; ++u) {
      float z1 = xlo[u], z2 = xhi[u];
      const float4* hp4 = (const float4*)(hb + dir * 256 + buf * H_N);
      for (int k4 = 0; k4 < 32; k4++) {
        float4 h4 = hp4[k4];
        float4 wa = *(const float4*)(W4 + (size_t)(k4 * 512 + g1) * 4);
        float4 wb = *(const float4*)(W4 + (size_t)(k4 * 512 + g1 + 256) * 4);
        z1 += h4.x * wa.x + h4.y * wa.y + h4.z * wa.z + h4.w * wa.w;
        z2 += h4.x * wb.x + h4.y * wb.y + h4.z * wb.z + h4.w * wb.w;
      }
      float gi = 0.0f, gg = 0.0f;
      if (g1 < H_N) { gi = sigf(z1); gg = tanhf(z2); }                       // i, g gates
      else { gFb[dir * H_N + (g1 - H_N)] = sigf(z1); gOb[dir * H_N + (g1 - H_N)] = sigf(z2); }  // f, o
      __syncthreads();
      if (g1 < H_N) {
        c = gFb[dir * H_N + g1] * c + gi * gg;
        float hv = gOb[dir * H_N + g1] * tanhf(c);
        hb[dir * 256 + (buf ^ 1) * H_N + g1] = hv;
        int row = memb_s[u ^ dmask];               // fwd: u; bwd: 15-u (rev-aligned)
        thoughts[(size_t)row * TD_N + dir * H_N + g1] = hv;
      }
      __syncthreads();
      buf ^= 1;
    }
    __threadfence();
    __syncthreads();
    if (tid < 16)
      __hip_atomic_fetch_add(&ver[memb_s[tid]], 1, __ATOMIC_RELEASE, __HIP_MEMORY_SCOPE_AGENT);
    __syncthreads();
  }
}

// ---------------- k_actor2: acts = tanh(LN(LN(relu(th)@W3+b3)@W4+b4)), in-place th==out ----------------
__global__ __launch_bounds__(256) void k_actor2(const float* __restrict__ th,
    const float* __restrict__ W3, const float* __restrict__ b3,
    const float* __restrict__ g3, const float* __restrict__ bt3,
    const float* __restrict__ W4, const float* __restrict__ b4,
    const float* __restrict__ g4, const float* __restrict__ bt4,
    float* __restrict__ out) {
  __shared__ float Hs[4 * TD_N];
  __shared__ float H3[4 * TD_N];
  __shared__ float red[4][4][2];
  int tid = threadIdx.x;
  int r0 = blockIdx.x * 4;
  int j = tid;
  for (int i = tid; i < 4 * TD_N; i += 256) Hs[i] = fmaxf(th[(size_t)r0 * TD_N + i], 0.0f);
  __syncthreads();  // all reads of own rows complete before any write below
  float z[4] = {0, 0, 0, 0};
  {
    const float4* S4 = (const float4*)Hs;
    for (int k4 = 0; k4 < 64; k4++) {
      float w0 = W3[(k4 * 4 + 0) * TD_N + j];
      float w1 = W3[(k4 * 4 + 1) * TD_N + j];
      float w2 = W3[(k4 * 4 + 2) * TD_N + j];
      float w3v = W3[(k4 * 4 + 3) * TD_N + j];
#pragma unroll
      for (int r = 0; r < 4; r++) {
        float4 sv = S4[r * 64 + k4];
        z[r] += sv.x * w0 + sv.y * w1 + sv.z * w2 + sv.w * w3v;
      }
    }
  }
  for (int r = 0; r < 4; r++) z[r] += b3[j];
  int w = tid >> 6, lane = tid & 63;
  for (int r = 0; r < 4; r++) {
    float v = z[r], v2 = z[r] * z[r];
    for (int off = 32; off; off >>= 1) { v += __shfl_down(v, off); v2 += __shfl_down(v2, off); }
    if (lane == 0) { red[r][w][0] = v; red[r][w][1] = v2; }
  }
  __syncthreads();
  for (int r = 0; r < 4; r++) {
    float sm = red[r][0][0] + red[r][1][0] + red[r][2][0] + red[r][3][0];
    float sq = red[r][0][1] + red[r][1][1] + red[r][2][1] + red[r][3][1];
    float mean = sm * (1.0f / TD_N);
    float var = sq * (1.0f / TD_N) - mean * mean;
    float rs = 1.0f / sqrtf(var + 1e-5f);
    H3[r * TD_N + j] = (z[r] - mean) * rs * g3[j] + bt3[j];
  }
  __syncthreads();
  float z2a[4] = {0, 0, 0, 0};
  {
    const float4* S4 = (const float4*)H3;
    for (int k4 = 0; k4 < 64; k4++) {
      float w0 = W4[(k4 * 4 + 0) * TD_N + j];
      float w1 = W4[(k4 * 4 + 1) * TD_N + j];
      float w2 = W4[(k4 * 4 + 2) * TD_N + j];
      float w3v = W4[(k4 * 4 + 3) * TD_N + j];
#pragma unroll
      for (int r = 0; r < 4; r++) {
        float4 sv = S4[r * 64 + k4];
        z2a[r] += sv.x * w0 + sv.y * w1 + sv.z * w2 + sv.w * w3v;
      }
    }
  }
  for (int r = 0; r < 4; r++) z2a[r] += b4[j];
  __syncthreads();
  for (int r = 0; r < 4; r++) {
    float v = z2a[r], v2 = z2a[r] * z2a[r];
    for (int off = 32; off; off >>= 1) { v += __shfl_down(v, off); v2 += __shfl_down(v2, off); }
    if (lane == 0) { red[r][w][0] = v; red[r][w][1] = v2; }
  }
  __syncthreads();
  for (int r = 0; r < 4; r++) {
    float sm = red[r][0][0] + red[r][1][0] + red[r][2][0] + red[r][3][0];
    float sq = red[r][0][1] + red[r][1][1] + red[r][2][1] + red[r][3][1];
    float mean = sm * (1.0f / TD_N);
    float var = sq * (1.0f / TD_N) - mean * mean;
    float rs = 1.0f / sqrtf(var + 1e-5f);
    float val = (z2a[r] - mean) * rs * g4[j] + bt4[j];
    out[(size_t)(r0 + r) * TD_N + j] = tanhf(val);
  }
}

extern "C" void kernel_launch(void* const* d_in, const int* in_sizes, int n_in,
                              void* d_out, int out_size, void* d_ws, size_t ws_size,
                              hipStream_t stream) {
  const float* obs = (const float*)d_in[0];
  const unsigned char* C = (const unsigned char*)d_in[1];
  const float* W1 = (const float*)d_in[2];  const float* b1 = (const float*)d_in[3];
  const float* g1 = (const float*)d_in[4];  const float* bt1 = (const float*)d_in[5];
  const float* W2 = (const float*)d_in[6];  const float* b2 = (const float*)d_in[7];
  const float* g2 = (const float*)d_in[8];  const float* bt2 = (const float*)d_in[9];
  const float* aW1 = (const float*)d_in[10]; const float* ab1 = (const float*)d_in[11];
  const float* aW2 = (const float*)d_in[12]; const float* ab2 = (const float*)d_in[13];
  const float* aW3 = (const float*)d_in[14]; const float* ab3 = (const float*)d_in[15];
  const float* Wih_f = (const float*)d_in[16]; const float* Whh_f = (const float*)d_in[17];
  const float* bih_f = (const float*)d_in[18]; const float* bhh_f = (const float*)d_in[19];
  const float* Wih_r = (const float*)d_in[20]; const float* Whh_r = (const float*)d_in[21];
  const float* bih_r = (const float*)d_in[22]; const float* bhh_r = (const float*)d_in[23];
  const float* W3 = (const float*)d_in[24]; const float* b3 = (const float*)d_in[25];
  const float* g3 = (const float*)d_in[26]; const float* bt3 = (const float*)d_in[27];
  const float* W4 = (const float*)d_in[28]; const float* b4 = (const float*)d_in[29];
  const float* g4 = (const float*)d_in[30]; const float* bt4 = (const float*)d_in[31];
  float* out = (float*)d_out;

  // Workspace layout (floats). thoughts lives in d_out; t_buf overlaps the
  // weight region (t_buf dead before k_prep writes weights).
  float* ws = (float*)d_ws;
  float* Wih4f = ws;                 // [0, 131072)
  float* Wih4r = ws + 131072;        // [131072, 262144)
  float* Whh4f = ws + 262144;        // [262144, 327680)
  float* Whh4r = ws + 327680;        // [327680, 393216)
  float* bsumf = ws + 393216;        // 512
  float* bsumr = ws + 393728;        // 512
  float* t_buf = ws;                 // phase-1 only, 262144 floats (overlaps Wih4*)
  int* membi   = (int*)(ws + 394240);       // 16384
  int* reqi    = membi + 16384;             // 16384
  int* isin    = reqi + 16384;              // 1024
  int* ver     = isin + 1024;               // 1024
  int* flag    = ver + 1024;                // 64 (padded)
  size_t need = (size_t)(394240 + 34880) * 4;  // ~1.72 MB
  if (ws_size < need) return;  // diagnosable absmax-fail instead of a fault

  (void)in_sizes; (void)n_in; (void)out_size;

  float* th = out;  // thoughts buffer aliases d_out (same shape/dtype)

  k_cdet<<<1, 64, 0, stream>>>(C, flag);
  k_actor1a<<<256, 256, 0, stream>>>(obs, W1, b1, g1, bt1, t_buf);
  k_actor1b<<<256, 256, 0, stream>>>(t_buf, W2, b2, g2, bt2, th);
  k_att<<<256, 256, 0, stream>>>(th, aW1, ab1, aW2, ab2, aW3, ab3, isin);
  k_memb<<<1024, 64, 0, stream>>>(C, flag, membi);
  k_req<<<1024, 256, 0, stream>>>(C, flag, membi, isin, reqi);
  k_prep<<<512, 256, 0, stream>>>(Wih_f, Wih_r, Whh_f, Whh_r, bih_f, bhh_f, bih_r, bhh_r,
                                  Wih4f, Wih4r, Whh4f, Whh4r, bsumf, bsumr, ver);
  k_comm<<<NWG, 512, 0, stream>>>(th, membi, reqi, isin, ver,
                                  Wih4f, Wih4r, Whh4f, Whh4r, bsumf, bsumr);
  k_actor2<<<256, 256, 0, stream>>>(th, W3, b3, g3, bt3, W4, b4, g4, bt4, out);
}

// Round 4
// 13739.555 us; speedup vs baseline: 17.9729x; 17.9729x over previous
//
#include <hip/hip_runtime.h>
#include <cstdint>
#include <cstddef>
#include <math.h>

#define A_N   1024
#define OBS_N 2048
#define TD_N  256
#define H_N   128
#define M_N   16
#define AE_N  64
#define MAXL  320

__device__ __forceinline__ float sigf(float x) { return 1.0f / (1.0f + expf(-x)); }

// C may arrive as uint8 (1B/elem) or int32 (4B/elem). Detect on device.
__device__ __forceinline__ bool c_at(const unsigned char* C, int as_int, size_t idx) {
  return as_int ? (((const int*)C)[idx] != 0) : (C[idx] != 0);
}

__global__ __launch_bounds__(64) void k_cdet(const unsigned char* __restrict__ C, int* __restrict__ flag) {
  int lane = threadIdx.x;
  int cnt = 0;
  for (int i = lane; i < 4096; i += 64) cnt += (C[i] != 0) ? 1 : 0;
  for (int off = 32; off; off >>= 1) cnt += __shfl_down(cnt, off);
  if (lane == 0) flag[0] = (cnt < 40) ? 1 : 0;
}

// ---------------- k1: t = relu(LN(obs@W1 + b1)) ----------------
__global__ __launch_bounds__(256) void k_actor1a(const float* __restrict__ obs,
    const float* __restrict__ W1, const float* __restrict__ b1,
    const float* __restrict__ g1, const float* __restrict__ bt1,
    float* __restrict__ tout) {
  __shared__ float S[4 * OBS_N];
  __shared__ float red[4][4][2];
  int tid = threadIdx.x;
  int r0 = blockIdx.x * 4;
  {
    const float4* src = (const float4*)(obs + (size_t)r0 * OBS_N);
    float4* dst = (float4*)S;
    for (int i = tid; i < 4 * OBS_N / 4; i += 256) dst[i] = src[i];
  }
  __syncthreads();
  int j = tid;
  float acc0 = 0, acc1 = 0, acc2 = 0, acc3 = 0;
  const float4* S4 = (const float4*)S;
  for (int k4 = 0; k4 < OBS_N / 4; k4++) {
    float w0 = W1[(k4 * 4 + 0) * TD_N + j];
    float w1 = W1[(k4 * 4 + 1) * TD_N + j];
    float w2 = W1[(k4 * 4 + 2) * TD_N + j];
    float w3 = W1[(k4 * 4 + 3) * TD_N + j];
    float4 s0 = S4[0 * 512 + k4], s1 = S4[1 * 512 + k4], s2 = S4[2 * 512 + k4], s3 = S4[3 * 512 + k4];
    acc0 += s0.x * w0 + s0.y * w1 + s0.z * w2 + s0.w * w3;
    acc1 += s1.x * w0 + s1.y * w1 + s1.z * w2 + s1.w * w3;
    acc2 += s2.x * w0 + s2.y * w1 + s2.z * w2 + s2.w * w3;
    acc3 += s3.x * w0 + s3.y * w1 + s3.z * w2 + s3.w * w3;
  }
  float z[4] = {acc0 + b1[j], acc1 + b1[j], acc2 + b1[j], acc3 + b1[j]};
  int w = tid >> 6, lane = tid & 63;
  for (int r = 0; r < 4; r++) {
    float v = z[r], v2 = z[r] * z[r];
    for (int off = 32; off; off >>= 1) { v += __shfl_down(v, off); v2 += __shfl_down(v2, off); }
    if (lane == 0) { red[r][w][0] = v; red[r][w][1] = v2; }
  }
  __syncthreads();
  for (int r = 0; r < 4; r++) {
    float sm = red[r][0][0] + red[r][1][0] + red[r][2][0] + red[r][3][0];
    float sq = red[r][0][1] + red[r][1][1] + red[r][2][1] + red[r][3][1];
    float mean = sm * (1.0f / TD_N);
    float var = sq * (1.0f / TD_N) - mean * mean;
    float rs = 1.0f / sqrtf(var + 1e-5f);
    float val = (z[r] - mean) * rs * g1[j] + bt1[j];
    tout[(size_t)(r0 + r) * TD_N + j] = fmaxf(val, 0.0f);
  }
}

// ---------------- k2: thoughts = LN(t@W2 + b2) -> thA (= d_out) ----------------
__global__ __launch_bounds__(256) void k_actor1b(const float* __restrict__ tin,
    const float* __restrict__ W2, const float* __restrict__ b2,
    const float* __restrict__ g2, const float* __restrict__ bt2,
    float* __restrict__ th) {
  __shared__ float S[4 * TD_N];
  __shared__ float red[4][4][2];
  int tid = threadIdx.x;
  int r0 = blockIdx.x * 4;
  for (int i = tid; i < 4 * TD_N; i += 256) S[i] = tin[(size_t)r0 * TD_N + i];
  __syncthreads();
  int j = tid;
  float z[4] = {0, 0, 0, 0};
  const float4* S4 = (const float4*)S;
  for (int k4 = 0; k4 < TD_N / 4; k4++) {
    float w0 = W2[(k4 * 4 + 0) * TD_N + j];
    float w1 = W2[(k4 * 4 + 1) * TD_N + j];
    float w2v = W2[(k4 * 4 + 2) * TD_N + j];
    float w3 = W2[(k4 * 4 + 3) * TD_N + j];
#pragma unroll
    for (int r = 0; r < 4; r++) {
      float4 sv = S4[r * 64 + k4];
      z[r] += sv.x * w0 + sv.y * w1 + sv.z * w2v + sv.w * w3;
    }
  }
  for (int r = 0; r < 4; r++) z[r] += b2[j];
  int w = tid >> 6, lane = tid & 63;
  for (int r = 0; r < 4; r++) {
    float v = z[r], v2 = z[r] * z[r];
    for (int off = 32; off; off >>= 1) { v += __shfl_down(v, off); v2 += __shfl_down(v2, off); }
    if (lane == 0) { red[r][w][0] = v; red[r][w][1] = v2; }
  }
  __syncthreads();
  for (int r = 0; r < 4; r++) {
    float sm = red[r][0][0] + red[r][1][0] + red[r][2][0] + red[r][3][0];
    float sq = red[r][0][1] + red[r][1][1] + red[r][2][1] + red[r][3][1];
    float mean = sm * (1.0f / TD_N);
    float var = sq * (1.0f / TD_N) - mean * mean;
    float rs = 1.0f / sqrtf(var + 1e-5f);
    th[(size_t)(r0 + r) * TD_N + j] = (z[r] - mean) * rs * g2[j] + bt2[j];
  }
}

// ---------------- k3: attention unit -> is_init (fp64: x>0 decision is razor-thin) ----------------
__global__ __launch_bounds__(256) void k_att(const float* __restrict__ th,
    const float* __restrict__ aW1, const float* __restrict__ ab1,
    const float* __restrict__ aW2, const float* __restrict__ ab2,
    const float* __restrict__ aW3, const float* __restrict__ ab3,
    int* __restrict__ isin) {
  __shared__ float S[4 * TD_N];
  __shared__ double A1[4 * AE_N];
  __shared__ double A2[4 * AE_N];
  int tid = threadIdx.x;
  int r0 = blockIdx.x * 4;
  for (int i = tid; i < 4 * TD_N; i += 256) S[i] = th[(size_t)r0 * TD_N + i];
  __syncthreads();
  int r = tid >> 6, c = tid & 63;
  double acc = 0;
  for (int k = 0; k < TD_N; k++) acc += (double)S[r * TD_N + k] * (double)aW1[k * AE_N + c];
  acc += (double)ab1[c];
  A1[r * AE_N + c] = acc > 0.0 ? acc : 0.0;
  __syncthreads();
  acc = 0;
  for (int k = 0; k < AE_N; k++) acc += A1[r * AE_N + k] * (double)aW2[k * AE_N + c];
  acc += (double)ab2[c];
  A2[r * AE_N + c] = acc > 0.0 ? acc : 0.0;
  __syncthreads();
  double p = A2[r * AE_N + c] * (double)aW3[c];
  for (int off = 32; off; off >>= 1) p += __shfl_down(p, off);
  if (c == 0) isin[r0 + r] = ((p + (double)ab3[0]) > 0.0) ? 1 : 0;
}

// ---------------- k_memb: member indices (ascending) per row ----------------
__global__ __launch_bounds__(64) void k_memb(const unsigned char* __restrict__ C,
    const int* __restrict__ flag, int* __restrict__ memb) {
  int s = blockIdx.x, lane = threadIdx.x;
  int as_int = flag[0];
  if (lane < M_N) memb[s * M_N + lane] = lane;  // safe defaults (never poison)
  __syncthreads();
  int base = 0;
  for (int ch = 0; ch < 16; ch++) {
    int col = ch * 64 + lane;
    bool v = c_at(C, as_int, (size_t)s * A_N + col);
    unsigned long long m = __ballot(v);
    if (v) {
      int pos = base + __popcll(m & ((1ull << lane) - 1ull));
      if (pos < M_N) memb[s * M_N + pos] = col;
    }
    base += __popcll(m);
  }
}

// ---------------- k_req: required count (= write ordinal) per (step, member slot) ----------------
__global__ __launch_bounds__(256) void k_req(const unsigned char* __restrict__ C,
    const int* __restrict__ flag, const int* __restrict__ memb,
    const int* __restrict__ isin, int* __restrict__ req) {
  __shared__ int Ls[A_N];
  int s = blockIdx.x, tid = threadIdx.x;
  int as_int = flag[0];
  for (int i = tid; i < A_N; i += 256) Ls[i] = isin[i];
  __syncthreads();
  int i = tid >> 4, sub = tid & 15;
  int m = memb[s * M_N + i] & (A_N - 1);
  int cnt = 0;
  for (int s2 = sub; s2 < s; s2 += 16)
    if (Ls[s2] && c_at(C, as_int, (size_t)s2 * A_N + m)) cnt++;
  for (int off = 1; off < 16; off <<= 1) cnt += __shfl_xor(cnt, off);
  if (sub == 0) req[s * M_N + i] = cnt;
}

// ---------------- k_prep: k-major weight re-layouts, bias sums, ver reset ----------------
__global__ __launch_bounds__(256) void k_prep(
    const float* __restrict__ Wih_f, const float* __restrict__ Wih_r,
    const float* __restrict__ Whh_f, const float* __restrict__ Whh_r,
    const float* __restrict__ bih_f, const float* __restrict__ bhh_f,
    const float* __restrict__ bih_r, const float* __restrict__ bhh_r,
    float* __restrict__ Wih4f, float* __restrict__ Wih4r,
    float* __restrict__ Whh4f, float* __restrict__ Whh4r,
    float* __restrict__ bsumf, float* __restrict__ bsumr, int* __restrict__ ver) {
  int id = blockIdx.x * 256 + threadIdx.x;  // 512*256 = 131072
  {
    int kk = id & 3, g = (id >> 2) & 511, k4 = id >> 11;
    Wih4f[id] = Wih_f[g * TD_N + k4 * 4 + kk];
    Wih4r[id] = Wih_r[g * TD_N + k4 * 4 + kk];
  }
  if (id < 65536) {
    int kk = id & 3, g = (id >> 2) & 511, k4 = id >> 11;
    Whh4f[id] = Whh_f[g * H_N + k4 * 4 + kk];
    Whh4r[id] = Whh_r[g * H_N + k4 * 4 + kk];
  }
  if (id < 512) { bsumf[id] = bih_f[id] + bhh_f[id]; bsumr[id] = bih_r[id] + bhh_r[id]; }
  if (id < A_N) ver[id] = 0;
}

// ---------------- k_lvl: topological levels + buckets + final parity (single wave) ----------------
__global__ __launch_bounds__(64) void k_lvl(const int* __restrict__ isin,
    const int* __restrict__ memb, int* __restrict__ lvl_g, int* __restrict__ fin,
    int* __restrict__ lstart, int* __restrict__ llist) {
  __shared__ int last[A_N];
  __shared__ unsigned char cntm[A_N];
  __shared__ short lvlS[A_N];
  __shared__ int cnt[MAXL + 2];
  __shared__ int cur[MAXL + 2];
  int lane = threadIdx.x;
  for (int i = lane; i < A_N; i += 64) { last[i] = 0; cntm[i] = 0; lvlS[i] = 0; }
  for (int l = lane; l < MAXL + 2; l += 64) cnt[l] = 0;
  __syncthreads();
  for (int s = 0; s < A_N; s++) {
    if (isin[s]) {
      int li = 0, m = 0;
      if (lane < 16) { m = memb[s * M_N + lane] & (A_N - 1); li = last[m]; }
      for (int off = 8; off; off >>= 1) li = max(li, __shfl_xor(li, off));
      int L = __shfl(li, 0) + 1;
      if (lane < 16) { last[m] = L; cntm[m]++; }
      if (lane == 0) { lvlS[s] = (short)L; int b = (L > MAXL) ? (MAXL + 1) : L; cnt[b]++; }
    }
    __syncthreads();
  }
  if (lane == 0) {
    int acc = 0;
    for (int L = 1; L <= MAXL + 1; L++) { cur[L] = acc; lstart[L] = acc; acc += cnt[L]; }
  }
  __syncthreads();
  if (lane == 0) {
    for (int s = 0; s < A_N; s++) {
      int L = lvlS[s];
      if (L > 0) { int b = (L > MAXL) ? (MAXL + 1) : L; llist[cur[b]++] = s; }
    }
  }
  for (int i = lane; i < A_N; i += 64) { lvl_g[i] = lvlS[i]; fin[i] = cntm[i] & 1; }
}

// ---------------- k_step: one topological level; 2 WGs per step (one per LSTM dir) ----------------
// Race-free by parity ping-pong: step's n-th write of row m reads buffer (n&1), writes (n&1)^1.
// No atomics (except ver bump for catch-all), no fences, no polling.
__global__ __launch_bounds__(512, 2) void k_step(int L,
    float* __restrict__ thA, float* __restrict__ thB,
    const int* __restrict__ lstart, const int* __restrict__ llist,
    const int* __restrict__ memb, const int* __restrict__ req, int* __restrict__ ver,
    const float* __restrict__ Wih4f, const float* __restrict__ Wih4r,
    const float* __restrict__ Whh4f, const float* __restrict__ Whh4r,
    const float* __restrict__ bsumf, const float* __restrict__ bsumr) {
  int i0 = lstart[L], i1 = lstart[L + 1];
  int nst = i1 - i0;
  if (nst <= 0) return;
  __shared__ float S[16 * TD_N];     // 16 KB
  __shared__ float garr[4 * H_N];    // i,f,g,o  2 KB
  __shared__ float hb[2 * H_N];      // ping-pong h  1 KB
  __shared__ int memb_s[16];
  __shared__ int par_s[16];
  int tid = threadIdx.x;
  int dir = blockIdx.x & 1;
  int dmask = dir ? 15 : 0;
  const float* Wih4 = dir ? Wih4r : Wih4f;
  const float* Whh4 = dir ? Whh4r : Whh4f;
  float blo = (dir ? bsumr : bsumf)[tid];
  // hoist this thread's Whh column into registers (reused 16x per step, all steps)
  float4 wcol[32];
#pragma unroll
  for (int k4 = 0; k4 < 32; k4++) wcol[k4] = *(const float4*)(Whh4 + (size_t)(k4 * 512 + tid) * 4);

  for (int pi = (int)(blockIdx.x >> 1); pi < nst; pi += (int)(gridDim.x >> 1)) {
    int s = llist[i0 + pi];
    if (tid < 16) { memb_s[tid] = memb[s * M_N + tid] & (A_N - 1); par_s[tid] = req[s * M_N + tid] & 1; }
    __syncthreads();
    {  // gather 16 member rows from their parity buffers
      int r = tid >> 5, p = tid & 31;
      const float* src = (par_s[r] ? thB : thA) + (size_t)memb_s[r] * TD_N + p * 8;
      float4 a = ((const float4*)src)[0], b = ((const float4*)src)[1];
      *(float4*)(S + r * TD_N + p * 8) = a;
      *(float4*)(S + r * TD_N + p * 8 + 4) = b;
    }
    __syncthreads();
    // input transform: thread owns gate-col tid of its dir; xcol[t] in registers
    float xcol[16];
#pragma unroll
    for (int t = 0; t < 16; t++) xcol[t] = blo;
    {
      const float4* S4 = (const float4*)S;
      for (int k4 = 0; k4 < 64; k4++) {
        float4 wv = *(const float4*)(Wih4 + (size_t)(k4 * 512 + tid) * 4);
#pragma unroll
        for (int t = 0; t < 16; t++) {
          float4 sv = S4[(t ^ dmask) * 64 + k4];
          xcol[t] += sv.x * wv.x + sv.y * wv.y + sv.z * wv.z + sv.w * wv.w;
        }
      }
    }
    if (tid < H_N) hb[tid] = 0.0f;  // h0 = 0 (buf 0)
    __syncthreads();
    float cst = 0.0f;
    int buf = 0;
#pragma unroll
    for (int u = 0; u < 16; u++) {
      float z = xcol[u];
      const float4* hp4 = (const float4*)(hb + buf * H_N);
#pragma unroll
      for (int k4 = 0; k4 < 32; k4++) {
        float4 h4 = hp4[k4];
        float4 wv = wcol[k4];
        z += h4.x * wv.x + h4.y * wv.y + h4.z * wv.z + h4.w * wv.w;
      }
      garr[tid] = ((tid >> 7) == 2) ? tanhf(z) : sigf(z);  // gate order i,f,g,o
      __syncthreads();
      if (tid < H_N) {
        cst = garr[H_N + tid] * cst + garr[tid] * garr[2 * H_N + tid];
        float hv = garr[3 * H_N + tid] * tanhf(cst);
        hb[(buf ^ 1) * H_N + tid] = hv;
        int r = u ^ dmask;                      // fwd: u; bwd: 15-u (rev-aligned)
        float* dst = par_s[r] ? thA : thB;      // write opposite buffer
        dst[(size_t)memb_s[r] * TD_N + dir * H_N + tid] = hv;
      }
      __syncthreads();
      buf ^= 1;
    }
    if (dir == 0 && tid < 16) atomicAdd(&ver[memb_s[tid]], 1);  // for catch-all only
    __syncthreads();
  }
}

// ---------------- k_comm: catch-all for steps with level > MAXL (expected: none) ----------------
__global__ __launch_bounds__(512) void k_comm(float* __restrict__ thA, float* __restrict__ thB,
    const int* __restrict__ memb, const int* __restrict__ req,
    const int* __restrict__ lvl, int* __restrict__ ver,
    const float* __restrict__ Wih4f, const float* __restrict__ Wih4r,
    const float* __restrict__ Whh4f, const float* __restrict__ Whh4r,
    const float* __restrict__ bsumf, const float* __restrict__ bsumr) {
  __shared__ float S[16 * TD_N];
  __shared__ float hb[2 * 2 * H_N];
  __shared__ float gFb[2 * H_N];
  __shared__ float gOb[2 * H_N];
  __shared__ int memb_s[16];
  __shared__ int par_s[16];
  int tid = threadIdx.x;
  int dir = tid >> 8, g1 = tid & 255;
  int dmask = dir ? 15 : 0;
  const float* Wih4 = dir ? Wih4r : Wih4f;
  const float* W4   = dir ? Whh4r : Whh4f;
  const float* bsum = dir ? bsumr : bsumf;

  for (int s = blockIdx.x; s < A_N; s += 256) {
    if (lvl[s] <= MAXL) continue;  // handled by level kernels (or inactive)
    if (tid < 16) { memb_s[tid] = memb[s * M_N + tid] & (A_N - 1); par_s[tid] = req[s * M_N + tid] & 1; }
    __syncthreads();
    if (tid < 16) {
      int m = memb_s[tid], rq = req[s * M_N + tid];
      int tries = 0;
      while (__hip_atomic_load(&ver[m], __ATOMIC_ACQUIRE, __HIP_MEMORY_SCOPE_AGENT) < rq) {
        __builtin_amdgcn_s_sleep(32);
        if (++tries > (1 << 20)) break;
      }
    }
    __syncthreads();
    {
      int r = tid >> 5, p = tid & 31;
      const float* src = (par_s[r] ? thB : thA) + (size_t)memb_s[r] * TD_N + p * 8;
      float4 a = ((const float4*)src)[0], b = ((const float4*)src)[1];
      *(float4*)(S + r * TD_N + p * 8) = a;
      *(float4*)(S + r * TD_N + p * 8 + 4) = b;
    }
    __syncthreads();
    float xlo[16], xhi[16];
    {
      float blo = bsum[g1], bhi = bsum[g1 + 256];
#pragma unroll
      for (int t = 0; t < 16; t++) { xlo[t] = blo; xhi[t] = bhi; }
      const float4* S4 = (const float4*)S;
      for (int k4 = 0; k4 < 64; k4++) {
        float4 wlo = *(const float4*)(Wih4 + (size_t)(k4 * 512 + g1) * 4);
        float4 whi = *(const float4*)(Wih4 + (size_t)(k4 * 512 + g1 + 256) * 4);
#pragma unroll
        for (int t = 0; t < 16; t++) {
          float4 sv = S4[(t ^ dmask) * 64 + k4];
          xlo[t] += sv.x * wlo.x + sv.y * wlo.y + sv.z * wlo.z + sv.w * wlo.w;
          xhi[t] += sv.x * whi.x + sv.y * whi.y + sv.z * whi.z + sv.w * whi.w;
        }
      }
    }
    if (g1 < H_N) hb[dir * 256 + g1] = 0.0f;
    __syncthreads();
    float c = 0.0f;
    int buf = 0;
#pragma unroll
    for (int u = 0; u < 16; ++u) {
      float z1 = xlo[u], z2 = xhi[u];
      const float4* hp4 = (const float4*)(hb + dir * 256 + buf * H_N);
      for (int k4 = 0; k4 < 32; k4++) {
        float4 h4 = hp4[k4];
        float4 wa = *(const float4*)(W4 + (size_t)(k4 * 512 + g1) * 4);
        float4 wb = *(const float4*)(W4 + (size_t)(k4 * 512 + g1 + 256) * 4);
        z1 += h4.x * wa.x + h4.y * wa.y + h4.z * wa.z + h4.w * wa.w;
        z2 += h4.x * wb.x + h4.y * wb.y + h4.z * wb.z + h4.w * wb.w;
      }
      float gi = 0.0f, gg = 0.0f;
      if (g1 < H_N) { gi = sigf(z1); gg = tanhf(z2); }
      else { gFb[dir * H_N + (g1 - H_N)] = sigf(z1); gOb[dir * H_N + (g1 - H_N)] = sigf(z2); }
      __syncthreads();
      if (g1 < H_N) {
        c = gFb[dir * H_N + g1] * c + gi * gg;
        float hv = gOb[dir * H_N + g1] * tanhf(c);
        hb[dir * 256 + (buf ^ 1) * H_N + g1] = hv;
        int r = u ^ dmask;
        float* dst = par_s[r] ? thA : thB;
        dst[(size_t)memb_s[r] * TD_N + dir * H_N + g1] = hv;
      }
      __syncthreads();
      buf ^= 1;
    }
    __threadfence();
    __syncthreads();
    if (tid < 16)
      __hip_atomic_fetch_add(&ver[memb_s[tid]], 1, __ATOMIC_RELEASE, __HIP_MEMORY_SCOPE_AGENT);
    __syncthreads();
  }
}

// ---------------- k_actor2: acts = tanh(LN(LN(relu(th)@W3+b3)@W4+b4)), fin-parity gather ----------------
__global__ __launch_bounds__(256) void k_actor2(const float* __restrict__ thA, const float* __restrict__ thB,
    const int* __restrict__ fin,
    const float* __restrict__ W3, const float* __restrict__ b3,
    const float* __restrict__ g3, const float* __restrict__ bt3,
    const float* __restrict__ W4, const float* __restrict__ b4,
    const float* __restrict__ g4, const float* __restrict__ bt4,
    float* __restrict__ out) {
  __shared__ float Hs[4 * TD_N];
  __shared__ float H3[4 * TD_N];
  __shared__ float red[4][4][2];
  int tid = threadIdx.x;
  int r0 = blockIdx.x * 4;
  int j = tid;
  for (int i = tid; i < 4 * TD_N; i += 256) {
    int r = i >> 8, col = i & 255;
    int row = r0 + r;
    const float* src = fin[row] ? thB : thA;
    Hs[i] = fmaxf(src[(size_t)row * TD_N + col], 0.0f);
  }
  __syncthreads();  // all reads of own rows complete before any write below
  float z[4] = {0, 0, 0, 0};
  {
    const float4* S4 = (const float4*)Hs;
    for (int k4 = 0; k4 < 64; k4++) {
      float w0 = W3[(k4 * 4 + 0) * TD_N + j];
      float w1 = W3[(k4 * 4 + 1) * TD_N + j];
      float w2 = W3[(k4 * 4 + 2) * TD_N + j];
      float w3v = W3[(k4 * 4 + 3) * TD_N + j];
#pragma unroll
      for (int r = 0; r < 4; r++) {
        float4 sv = S4[r * 64 + k4];
        z[r] += sv.x * w0 + sv.y * w1 + sv.z * w2 + sv.w * w3v;
      }
    }
  }
  for (int r = 0; r < 4; r++) z[r] += b3[j];
  int w = tid >> 6, lane = tid & 63;
  for (int r = 0; r < 4; r++) {
    float v = z[r], v2 = z[r] * z[r];
    for (int off = 32; off; off >>= 1) { v += __shfl_down(v, off); v2 += __shfl_down(v2, off); }
    if (lane == 0) { red[r][w][0] = v; red[r][w][1] = v2; }
  }
  __syncthreads();
  for (int r = 0; r < 4; r++) {
    float sm = red[r][0][0] + red[r][1][0] + red[r][2][0] + red[r][3][0];
    float sq = red[r][0][1] + red[r][1][1] + red[r][2][1] + red[r][3][1];
    float mean = sm * (1.0f / TD_N);
    float var = sq * (1.0f / TD_N) - mean * mean;
    float rs = 1.0f / sqrtf(var + 1e-5f);
    H3[r * TD_N + j] = (z[r] - mean) * rs * g3[j] + bt3[j];
  }
  __syncthreads();
  float z2a[4] = {0, 0, 0, 0};
  {
    const float4* S4 = (const float4*)H3;
    for (int k4 = 0; k4 < 64; k4++) {
      float w0 = W4[(k4 * 4 + 0) * TD_N + j];
      float w1 = W4[(k4 * 4 + 1) * TD_N + j];
      float w2 = W4[(k4 * 4 + 2) * TD_N + j];
      float w3v = W4[(k4 * 4 + 3) * TD_N + j];
#pragma unroll
      for (int r = 0; r < 4; r++) {
        float4 sv = S4[r * 64 + k4];
        z2a[r] += sv.x * w0 + sv.y * w1 + sv.z * w2 + sv.w * w3v;
      }
    }
  }
  for (int r = 0; r < 4; r++) z2a[r] += b4[j];
  __syncthreads();
  for (int r = 0; r < 4; r++) {
    float v = z2a[r], v2 = z2a[r] * z2a[r];
    for (int off = 32; off; off >>= 1) { v += __shfl_down(v, off); v2 += __shfl_down(v2, off); }
    if (lane == 0) { red[r][w][0] = v; red[r][w][1] = v2; }
  }
  __syncthreads();
  for (int r = 0; r < 4; r++) {
    float sm = red[r][0][0] + red[r][1][0] + red[r][2][0] + red[r][3][0];
    float sq = red[r][0][1] + red[r][1][1] + red[r][2][1] + red[r][3][1];
    float mean = sm * (1.0f / TD_N);
    float var = sq * (1.0f / TD_N) - mean * mean;
    float rs = 1.0f / sqrtf(var + 1e-5f);
    float val = (z2a[r] - mean) * rs * g4[j] + bt4[j];
    out[(size_t)(r0 + r) * TD_N + j] = tanhf(val);
  }
}

extern "C" void kernel_launch(void* const* d_in, const int* in_sizes, int n_in,
                              void* d_out, int out_size, void* d_ws, size_t ws_size,
                              hipStream_t stream) {
  const float* obs = (const float*)d_in[0];
  const unsigned char* C = (const unsigned char*)d_in[1];
  const float* W1 = (const float*)d_in[2];  const float* b1 = (const float*)d_in[3];
  const float* g1 = (const float*)d_in[4];  const float* bt1 = (const float*)d_in[5];
  const float* W2 = (const float*)d_in[6];  const float* b2 = (const float*)d_in[7];
  const float* g2 = (const float*)d_in[8];  const float* bt2 = (const float*)d_in[9];
  const float* aW1 = (const float*)d_in[10]; const float* ab1 = (const float*)d_in[11];
  const float* aW2 = (const float*)d_in[12]; const float* ab2 = (const float*)d_in[13];
  const float* aW3 = (const float*)d_in[14]; const float* ab3 = (const float*)d_in[15];
  const float* Wih_f = (const float*)d_in[16]; const float* Whh_f = (const float*)d_in[17];
  const float* bih_f = (const float*)d_in[18]; const float* bhh_f = (const float*)d_in[19];
  const float* Wih_r = (const float*)d_in[20]; const float* Whh_r = (const float*)d_in[21];
  const float* bih_r = (const float*)d_in[22]; const float* bhh_r = (const float*)d_in[23];
  const float* W3 = (const float*)d_in[24]; const float* b3 = (const float*)d_in[25];
  const float* g3 = (const float*)d_in[26]; const float* bt3 = (const float*)d_in[27];
  const float* W4 = (const float*)d_in[28]; const float* b4 = (const float*)d_in[29];
  const float* g4 = (const float*)d_in[30]; const float* bt4 = (const float*)d_in[31];
  float* out = (float*)d_out;

  // Workspace layout (float offsets). t_buf overlaps thB (t_buf dead before k_step runs).
  float* ws = (float*)d_ws;
  float* Wih4f = ws;                  // 131072
  float* Wih4r = ws + 131072;         // 131072
  float* Whh4f = ws + 262144;         // 65536
  float* Whh4r = ws + 327680;         // 65536
  float* bsumf = ws + 393216;         // 512
  float* bsumr = ws + 393728;         // 512
  float* thB   = ws + 394240;         // 262144 (parity-1 thoughts buffer)
  float* t_buf = ws + 394240;         // overlap: used only before k_prep/k_step
  int* ibase   = (int*)(ws + 656384);
  int* membi   = ibase;               // 16384
  int* reqi    = ibase + 16384;       // 16384
  int* isin    = ibase + 32768;       // 1024
  int* ver     = ibase + 33792;       // 1024
  int* flag    = ibase + 34816;       // 64
  int* lvl     = ibase + 34880;       // 1024
  int* fin     = ibase + 35904;       // 1024
  int* lstart  = ibase + 36928;       // 512 (MAXL+2 used)
  int* llist   = ibase + 37440;       // 1024
  size_t need = (size_t)(656384 + 38464 + 64) * 4;  // ~2.78 MB
  if (ws_size < need) return;  // diagnosable absmax-fail instead of a fault

  (void)in_sizes; (void)n_in; (void)out_size;

  float* thA = out;  // parity-0 thoughts buffer aliases d_out

  k_cdet<<<1, 64, 0, stream>>>(C, flag);
  k_actor1a<<<256, 256, 0, stream>>>(obs, W1, b1, g1, bt1, t_buf);
  k_actor1b<<<256, 256, 0, stream>>>(t_buf, W2, b2, g2, bt2, thA);
  k_att<<<256, 256, 0, stream>>>(thA, aW1, ab1, aW2, ab2, aW3, ab3, isin);
  k_memb<<<1024, 64, 0, stream>>>(C, flag, membi);
  k_req<<<1024, 256, 0, stream>>>(C, flag, membi, isin, reqi);
  k_prep<<<512, 256, 0, stream>>>(Wih_f, Wih_r, Whh_f, Whh_r, bih_f, bhh_f, bih_r, bhh_r,
                                  Wih4f, Wih4r, Whh4f, Whh4r, bsumf, bsumr, ver);
  k_lvl<<<1, 64, 0, stream>>>(isin, membi, lvl, fin, lstart, llist);
  for (int L = 1; L <= MAXL; L++)
    k_step<<<64, 512, 0, stream>>>(L, thA, thB, lstart, llist, membi, reqi, ver,
                                   Wih4f, Wih4r, Whh4f, Whh4r, bsumf, bsumr);
  k_comm<<<256, 512, 0, stream>>>(thA, thB, membi, reqi, lvl, ver,
                                  Wih4f, Wih4r, Whh4f, Whh4r, bsumf, bsumr);
  k_actor2<<<256, 256, 0, stream>>>(thA, thB, fin, W3, b3, g3, bt3, W4, b4, g4, bt4, out);
}

// Round 5
// 12695.892 us; speedup vs baseline: 19.4503x; 1.0822x over previous
//
#include <hip/hip_runtime.h>
#include <cstdint>
#include <cstddef>
#include <math.h>

#define A_N   1024
#define OBS_N 2048
#define TD_N  256
#define H_N   128
#define M_N   16
#define AE_N  64
#define NWGC  64   // k_scan grid: 64 WGs <= 256 CUs -> co-residency guaranteed

typedef float v2f __attribute__((ext_vector_type(2)));

__device__ __forceinline__ float sigf(float x) { return 1.0f / (1.0f + expf(-x)); }

// C may arrive as uint8 (1B/elem) or int32 (4B/elem). Detect on device.
__device__ __forceinline__ bool c_at(const unsigned char* C, int as_int, size_t idx) {
  return as_int ? (((const int*)C)[idx] != 0) : (C[idx] != 0);
}

__global__ __launch_bounds__(64) void k_cdet(const unsigned char* __restrict__ C, int* __restrict__ flag) {
  int lane = threadIdx.x;
  int cnt = 0;
  for (int i = lane; i < 4096; i += 64) cnt += (C[i] != 0) ? 1 : 0;
  for (int off = 32; off; off >>= 1) cnt += __shfl_down(cnt, off);
  if (lane == 0) flag[0] = (cnt < 40) ? 1 : 0;
}

// ---------------- k1: t = relu(LN(obs@W1 + b1)) ----------------
__global__ __launch_bounds__(256) void k_actor1a(const float* __restrict__ obs,
    const float* __restrict__ W1, const float* __restrict__ b1,
    const float* __restrict__ g1, const float* __restrict__ bt1,
    float* __restrict__ tout) {
  __shared__ float S[4 * OBS_N];
  __shared__ float red[4][4][2];
  int tid = threadIdx.x;
  int r0 = blockIdx.x * 4;
  {
    const float4* src = (const float4*)(obs + (size_t)r0 * OBS_N);
    float4* dst = (float4*)S;
    for (int i = tid; i < 4 * OBS_N / 4; i += 256) dst[i] = src[i];
  }
  __syncthreads();
  int j = tid;
  float acc0 = 0, acc1 = 0, acc2 = 0, acc3 = 0;
  const float4* S4 = (const float4*)S;
  for (int k4 = 0; k4 < OBS_N / 4; k4++) {
    float w0 = W1[(k4 * 4 + 0) * TD_N + j];
    float w1 = W1[(k4 * 4 + 1) * TD_N + j];
    float w2 = W1[(k4 * 4 + 2) * TD_N + j];
    float w3 = W1[(k4 * 4 + 3) * TD_N + j];
    float4 s0 = S4[0 * 512 + k4], s1 = S4[1 * 512 + k4], s2 = S4[2 * 512 + k4], s3 = S4[3 * 512 + k4];
    acc0 += s0.x * w0 + s0.y * w1 + s0.z * w2 + s0.w * w3;
    acc1 += s1.x * w0 + s1.y * w1 + s1.z * w2 + s1.w * w3;
    acc2 += s2.x * w0 + s2.y * w1 + s2.z * w2 + s2.w * w3;
    acc3 += s3.x * w0 + s3.y * w1 + s3.z * w2 + s3.w * w3;
  }
  float z[4] = {acc0 + b1[j], acc1 + b1[j], acc2 + b1[j], acc3 + b1[j]};
  int w = tid >> 6, lane = tid & 63;
  for (int r = 0; r < 4; r++) {
    float v = z[r], v2 = z[r] * z[r];
    for (int off = 32; off; off >>= 1) { v += __shfl_down(v, off); v2 += __shfl_down(v2, off); }
    if (lane == 0) { red[r][w][0] = v; red[r][w][1] = v2; }
  }
  __syncthreads();
  for (int r = 0; r < 4; r++) {
    float sm = red[r][0][0] + red[r][1][0] + red[r][2][0] + red[r][3][0];
    float sq = red[r][0][1] + red[r][1][1] + red[r][2][1] + red[r][3][1];
    float mean = sm * (1.0f / TD_N);
    float var = sq * (1.0f / TD_N) - mean * mean;
    float rs = 1.0f / sqrtf(var + 1e-5f);
    float val = (z[r] - mean) * rs * g1[j] + bt1[j];
    tout[(size_t)(r0 + r) * TD_N + j] = fmaxf(val, 0.0f);
  }
}

// ---------------- k2: thoughts = LN(t@W2 + b2) -> thA (= d_out) ----------------
__global__ __launch_bounds__(256) void k_actor1b(const float* __restrict__ tin,
    const float* __restrict__ W2, const float* __restrict__ b2,
    const float* __restrict__ g2, const float* __restrict__ bt2,
    float* __restrict__ th) {
  __shared__ float S[4 * TD_N];
  __shared__ float red[4][4][2];
  int tid = threadIdx.x;
  int r0 = blockIdx.x * 4;
  for (int i = tid; i < 4 * TD_N; i += 256) S[i] = tin[(size_t)r0 * TD_N + i];
  __syncthreads();
  int j = tid;
  float z[4] = {0, 0, 0, 0};
  const float4* S4 = (const float4*)S;
  for (int k4 = 0; k4 < TD_N / 4; k4++) {
    float w0 = W2[(k4 * 4 + 0) * TD_N + j];
    float w1 = W2[(k4 * 4 + 1) * TD_N + j];
    float w2v = W2[(k4 * 4 + 2) * TD_N + j];
    float w3 = W2[(k4 * 4 + 3) * TD_N + j];
#pragma unroll
    for (int r = 0; r < 4; r++) {
      float4 sv = S4[r * 64 + k4];
      z[r] += sv.x * w0 + sv.y * w1 + sv.z * w2v + sv.w * w3;
    }
  }
  for (int r = 0; r < 4; r++) z[r] += b2[j];
  int w = tid >> 6, lane = tid & 63;
  for (int r = 0; r < 4; r++) {
    float v = z[r], v2 = z[r] * z[r];
    for (int off = 32; off; off >>= 1) { v += __shfl_down(v, off); v2 += __shfl_down(v2, off); }
    if (lane == 0) { red[r][w][0] = v; red[r][w][1] = v2; }
  }
  __syncthreads();
  for (int r = 0; r < 4; r++) {
    float sm = red[r][0][0] + red[r][1][0] + red[r][2][0] + red[r][3][0];
    float sq = red[r][0][1] + red[r][1][1] + red[r][2][1] + red[r][3][1];
    float mean = sm * (1.0f / TD_N);
    float var = sq * (1.0f / TD_N) - mean * mean;
    float rs = 1.0f / sqrtf(var + 1e-5f);
    th[(size_t)(r0 + r) * TD_N + j] = (z[r] - mean) * rs * g2[j] + bt2[j];
  }
}

// ---------------- k3: attention unit -> is_init (fp64: x>0 decision is razor-thin) ----------------
__global__ __launch_bounds__(256) void k_att(const float* __restrict__ th,
    const float* __restrict__ aW1, const float* __restrict__ ab1,
    const float* __restrict__ aW2, const float* __restrict__ ab2,
    const float* __restrict__ aW3, const float* __restrict__ ab3,
    int* __restrict__ isin) {
  __shared__ float S[4 * TD_N];
  __shared__ double A1[4 * AE_N];
  __shared__ double A2[4 * AE_N];
  int tid = threadIdx.x;
  int r0 = blockIdx.x * 4;
  for (int i = tid; i < 4 * TD_N; i += 256) S[i] = th[(size_t)r0 * TD_N + i];
  __syncthreads();
  int r = tid >> 6, c = tid & 63;
  double acc = 0;
  for (int k = 0; k < TD_N; k++) acc += (double)S[r * TD_N + k] * (double)aW1[k * AE_N + c];
  acc += (double)ab1[c];
  A1[r * AE_N + c] = acc > 0.0 ? acc : 0.0;
  __syncthreads();
  acc = 0;
  for (int k = 0; k < AE_N; k++) acc += A1[r * AE_N + k] * (double)aW2[k * AE_N + c];
  acc += (double)ab2[c];
  A2[r * AE_N + c] = acc > 0.0 ? acc : 0.0;
  __syncthreads();
  double p = A2[r * AE_N + c] * (double)aW3[c];
  for (int off = 32; off; off >>= 1) p += __shfl_down(p, off);
  if (c == 0) isin[r0 + r] = ((p + (double)ab3[0]) > 0.0) ? 1 : 0;
}

// ---------------- k_memb: member indices (ascending) per row ----------------
__global__ __launch_bounds__(64) void k_memb(const unsigned char* __restrict__ C,
    const int* __restrict__ flag, int* __restrict__ memb) {
  int s = blockIdx.x, lane = threadIdx.x;
  int as_int = flag[0];
  if (lane < M_N) memb[s * M_N + lane] = lane;  // safe defaults (never poison)
  __syncthreads();
  int base = 0;
  for (int ch = 0; ch < 16; ch++) {
    int col = ch * 64 + lane;
    bool v = c_at(C, as_int, (size_t)s * A_N + col);
    unsigned long long m = __ballot(v);
    if (v) {
      int pos = base + __popcll(m & ((1ull << lane) - 1ull));
      if (pos < M_N) memb[s * M_N + pos] = col;
    }
    base += __popcll(m);
  }
}

// ---------------- k_req: write ordinal per (step, member slot) ----------------
__global__ __launch_bounds__(256) void k_req(const unsigned char* __restrict__ C,
    const int* __restrict__ flag, const int* __restrict__ memb,
    const int* __restrict__ isin, int* __restrict__ req) {
  __shared__ int Ls[A_N];
  int s = blockIdx.x, tid = threadIdx.x;
  int as_int = flag[0];
  for (int i = tid; i < A_N; i += 256) Ls[i] = isin[i];
  __syncthreads();
  int i = tid >> 4, sub = tid & 15;
  int m = memb[s * M_N + i] & (A_N - 1);
  int cnt = 0;
  for (int s2 = sub; s2 < s; s2 += 16)
    if (Ls[s2] && c_at(C, as_int, (size_t)s2 * A_N + m)) cnt++;
  for (int off = 1; off < 16; off <<= 1) cnt += __shfl_xor(cnt, off);
  if (sub == 0) req[s * M_N + i] = cnt;
}

// ---------------- k_prep: k-major weight re-layouts, bias sums, barrier reset ----------------
__global__ __launch_bounds__(256) void k_prep(
    const float* __restrict__ Wih_f, const float* __restrict__ Wih_r,
    const float* __restrict__ Whh_f, const float* __restrict__ Whh_r,
    const float* __restrict__ bih_f, const float* __restrict__ bhh_f,
    const float* __restrict__ bih_r, const float* __restrict__ bhh_r,
    float* __restrict__ Wih4f, float* __restrict__ Wih4r,
    float* __restrict__ Whh4f, float* __restrict__ Whh4r,
    float* __restrict__ bsumf, float* __restrict__ bsumr, int* __restrict__ bar) {
  int id = blockIdx.x * 256 + threadIdx.x;  // 512*256 = 131072
  {
    int kk = id & 3, g = (id >> 2) & 511, k4 = id >> 11;
    Wih4f[id] = Wih_f[g * TD_N + k4 * 4 + kk];
    Wih4r[id] = Wih_r[g * TD_N + k4 * 4 + kk];
  }
  if (id < 65536) {
    int kk = id & 3, g = (id >> 2) & 511, k4 = id >> 11;
    Whh4f[id] = Whh_f[g * H_N + k4 * 4 + kk];
    Whh4r[id] = Whh_r[g * H_N + k4 * 4 + kk];
  }
  if (id < 512) { bsumf[id] = bih_f[id] + bhh_f[id]; bsumr[id] = bih_r[id] + bhh_r[id]; }
  if (id == 0) bar[0] = 0;
}

// ---------------- k_lvl: topological levels + buckets + final parity (single wave) ----------------
__global__ __launch_bounds__(64) void k_lvl(const int* __restrict__ isin,
    const int* __restrict__ memb, int* __restrict__ fin,
    int* __restrict__ lstart, int* __restrict__ llist) {
  __shared__ int last[A_N];
  __shared__ unsigned char cntm[A_N];
  __shared__ short lvlS[A_N];
  __shared__ int cnt[A_N + 2];
  __shared__ int cur[A_N + 2];
  int lane = threadIdx.x;
  for (int i = lane; i < A_N; i += 64) { last[i] = 0; cntm[i] = 0; lvlS[i] = 0; }
  for (int l = lane; l < A_N + 2; l += 64) cnt[l] = 0;
  __syncthreads();
  int lmax = 0;
  for (int s = 0; s < A_N; s++) {
    if (isin[s]) {
      int li = 0, m = 0;
      if (lane < 16) { m = memb[s * M_N + lane] & (A_N - 1); li = last[m]; }
#pragma unroll
      for (int off = 8; off; off >>= 1) li = max(li, __shfl_xor(li, off));
      int L = __shfl(li, 0) + 1;
      if (lane < 16) { last[m] = L; cntm[m]++; }
      if (lane == 0) { lvlS[s] = (short)L; cnt[L]++; }
      lmax = max(lmax, L);
    }
    __syncthreads();
  }
  if (lane == 0) {
    int acc = 0;
    for (int L = 1; L <= A_N + 1; L++) {
      cur[L] = acc; lstart[L] = acc;
      if (L <= A_N) acc += cnt[L];
    }
    lstart[0] = lmax;
  }
  __syncthreads();
  if (lane == 0) {
    for (int s = 0; s < A_N; s++) {
      int L = lvlS[s];
      if (L > 0) llist[cur[L]++] = s;
    }
  }
  for (int i = lane; i < A_N; i += 64) fin[i] = cntm[i] & 1;
}

// ---------------- k_scan: single-dispatch level-parallel scan ----------------
// 64 WGs (all co-resident). Per level: 2 WGs per step (one per LSTM dir),
// parity ping-pong th buffers (race-free), then a custom grid barrier:
//   arrive  = fetch_add RELEASE/AGENT (vmcnt0 + L2 writeback, ~nothing dirty)
//   poll    = RELAXED/AGENT loads (NO cache invalidate -> weights stay L2-warm;
//             this is what the R3 acquire-polling design destroyed)
// All th traffic uses relaxed agent-scope atomic ld/st (coherent at L3).
__global__ __launch_bounds__(512, 1) void k_scan(
    float* __restrict__ thA, float* __restrict__ thB,
    const int* __restrict__ lstart, const int* __restrict__ llist,
    const int* __restrict__ memb, const int* __restrict__ req, int* __restrict__ bar,
    const float* __restrict__ Wih4f, const float* __restrict__ Wih4r,
    const float* __restrict__ Whh4f, const float* __restrict__ Whh4r,
    const float* __restrict__ bsumf, const float* __restrict__ bsumr) {
  __shared__ float S[16 * TD_N];     // 16 KB
  __shared__ float garr[4 * H_N];    // gates i,f,g,o 2 KB
  __shared__ float hb[2 * H_N];      // h ping-pong 1 KB
  __shared__ int memb_s[16];
  __shared__ int par_s[16];
  int tid = threadIdx.x;
  int wg = blockIdx.x;
  int dir = wg & 1;
  int dmask = dir ? 15 : 0;
  const float* Wih4 = dir ? Wih4r : Wih4f;
  const float* Whh4 = dir ? Whh4r : Whh4f;
  float blo = (dir ? bsumr : bsumf)[tid];
  // hoist this thread's Whh gate-column into registers (reused every step)
  float4 wcol[32];
#pragma unroll
  for (int k4 = 0; k4 < 32; k4++) wcol[k4] = *(const float4*)(Whh4 + (size_t)(k4 * 512 + tid) * 4);

  int lmax = lstart[0];
  int round = 0;
  for (int L = 1; L <= lmax; L++) {
    int i0 = lstart[L], i1 = lstart[L + 1];
    for (int pi = wg >> 1; pi < i1 - i0; pi += NWGC >> 1) {
      int s = llist[i0 + pi];
      if (tid < 16) { memb_s[tid] = memb[s * M_N + tid] & (A_N - 1); par_s[tid] = req[s * M_N + tid] & 1; }
      __syncthreads();
      {  // gather 16 member rows (coherent loads from L3)
        int r = tid >> 5, p = tid & 31;
        const float* src = (par_s[r] ? thB : thA) + (size_t)memb_s[r] * TD_N + p * 8;
#pragma unroll
        for (int q = 0; q < 8; q++)
          S[r * TD_N + p * 8 + q] =
              __hip_atomic_load(src + q, __ATOMIC_RELAXED, __HIP_MEMORY_SCOPE_AGENT);
      }
      __syncthreads();
      // ---- input transform (packed fp32): xcol[t] = bsum + seq[t] . Wih[:,tid]
      v2f xa[16];
#pragma unroll
      for (int t = 0; t < 16; t++) xa[t] = (v2f){0.0f, 0.0f};
      {
        const float4* S4 = (const float4*)S;
        for (int k4 = 0; k4 < 64; k4++) {
          float4 wv = *(const float4*)(Wih4 + (size_t)(k4 * 512 + tid) * 4);
          v2f wlo = {wv.x, wv.y}, whi = {wv.z, wv.w};
#pragma unroll
          for (int t = 0; t < 16; t++) {
            float4 sv = S4[(t ^ dmask) * 64 + k4];
            xa[t] += (v2f){sv.x, sv.y} * wlo;
            xa[t] += (v2f){sv.z, sv.w} * whi;
          }
        }
      }
      float xcol[16];
#pragma unroll
      for (int t = 0; t < 16; t++) xcol[t] = blo + xa[t].x + xa[t].y;
      // ---- recurrence
      if (tid < H_N) hb[tid] = 0.0f;
      __syncthreads();
      float cst = 0.0f;
      int buf = 0;
#pragma unroll
      for (int u = 0; u < 16; u++) {
        v2f za = {0.0f, 0.0f}, zb = {0.0f, 0.0f};
        const float4* hp4 = (const float4*)(hb + buf * H_N);
#pragma unroll
        for (int k4 = 0; k4 < 32; k4 += 2) {
          float4 ha = hp4[k4], hc = hp4[k4 + 1];
          float4 wa = wcol[k4], wc = wcol[k4 + 1];
          za += (v2f){ha.x, ha.y} * (v2f){wa.x, wa.y};
          za += (v2f){ha.z, ha.w} * (v2f){wa.z, wa.w};
          zb += (v2f){hc.x, hc.y} * (v2f){wc.x, wc.y};
          zb += (v2f){hc.z, hc.w} * (v2f){wc.z, wc.w};
        }
        float z = xcol[u] + za.x + za.y + zb.x + zb.y;
        garr[tid] = ((tid >> 7) == 2) ? tanhf(z) : sigf(z);  // gate order i,f,g,o
        __syncthreads();
        if (tid < H_N) {
          cst = garr[H_N + tid] * cst + garr[tid] * garr[2 * H_N + tid];
          float hv = garr[3 * H_N + tid] * tanhf(cst);
          hb[(buf ^ 1) * H_N + tid] = hv;
          int r2 = u ^ dmask;                 // fwd: u; bwd: 15-u (rev-aligned)
          float* dst = par_s[r2] ? thA : thB; // write opposite parity buffer
          __hip_atomic_store(dst + (size_t)memb_s[r2] * TD_N + dir * H_N + tid, hv,
                             __ATOMIC_RELAXED, __HIP_MEMORY_SCOPE_AGENT);
        }
        __syncthreads();
        buf ^= 1;
      }
    }
    // ---- grid barrier (monotonic counter; relaxed polls keep L2 warm)
    round++;
    __syncthreads();
    if (tid == 0) {
      __hip_atomic_fetch_add(bar, 1, __ATOMIC_RELEASE, __HIP_MEMORY_SCOPE_AGENT);
      int tries = 0;
      while (__hip_atomic_load(bar, __ATOMIC_RELAXED, __HIP_MEMORY_SCOPE_AGENT) < round * NWGC) {
        __builtin_amdgcn_s_sleep(2);
        if (++tries > (1 << 14)) break;  // failsafe: wrong-answer beats hang
      }
    }
    __syncthreads();
  }
}

// ---------------- k_actor2: acts = tanh(LN(LN(relu(th)@W3+b3)@W4+b4)) ----------------
__global__ __launch_bounds__(256) void k_actor2(const float* __restrict__ thA, const float* __restrict__ thB,
    const int* __restrict__ fin,
    const float* __restrict__ W3, const float* __restrict__ b3,
    const float* __restrict__ g3, const float* __restrict__ bt3,
    const float* __restrict__ W4, const float* __restrict__ b4,
    const float* __restrict__ g4, const float* __restrict__ bt4,
    float* __restrict__ out) {
  __shared__ float Hs[4 * TD_N];
  __shared__ float H3[4 * TD_N];
  __shared__ float red[4][4][2];
  int tid = threadIdx.x;
  int r0 = blockIdx.x * 4;
  int j = tid;
  for (int i = tid; i < 4 * TD_N; i += 256) {
    int r = i >> 8, col = i & 255;
    int row = r0 + r;
    const float* src = (fin[row] ? thB : thA) + (size_t)row * TD_N + col;
    // coherent read: scan wrote th at L3 scope; avoid stale clean L2 lines
    float v = __hip_atomic_load(src, __ATOMIC_RELAXED, __HIP_MEMORY_SCOPE_AGENT);
    Hs[i] = fmaxf(v, 0.0f);
  }
  __syncthreads();  // all reads of own rows complete before any write below
  float z[4] = {0, 0, 0, 0};
  {
    const float4* S4 = (const float4*)Hs;
    for (int k4 = 0; k4 < 64; k4++) {
      float w0 = W3[(k4 * 4 + 0) * TD_N + j];
      float w1 = W3[(k4 * 4 + 1) * TD_N + j];
      float w2 = W3[(k4 * 4 + 2) * TD_N + j];
      float w3v = W3[(k4 * 4 + 3) * TD_N + j];
#pragma unroll
      for (int r = 0; r < 4; r++) {
        float4 sv = S4[r * 64 + k4];
        z[r] += sv.x * w0 + sv.y * w1 + sv.z * w2 + sv.w * w3v;
      }
    }
  }
  for (int r = 0; r < 4; r++) z[r] += b3[j];
  int w = tid >> 6, lane = tid & 63;
  for (int r = 0; r < 4; r++) {
    float v = z[r], v2 = z[r] * z[r];
    for (int off = 32; off; off >>= 1) { v += __shfl_down(v, off); v2 += __shfl_down(v2, off); }
    if (lane == 0) { red[r][w][0] = v; red[r][w][1] = v2; }
  }
  __syncthreads();
  for (int r = 0; r < 4; r++) {
    float sm = red[r][0][0] + red[r][1][0] + red[r][2][0] + red[r][3][0];
    float sq = red[r][0][1] + red[r][1][1] + red[r][2][1] + red[r][3][1];
    float mean = sm * (1.0f / TD_N);
    float var = sq * (1.0f / TD_N) - mean * mean;
    float rs = 1.0f / sqrtf(var + 1e-5f);
    H3[r * TD_N + j] = (z[r] - mean) * rs * g3[j] + bt3[j];
  }
  __syncthreads();
  float z2a[4] = {0, 0, 0, 0};
  {
    const float4* S4 = (const float4*)H3;
    for (int k4 = 0; k4 < 64; k4++) {
      float w0 = W4[(k4 * 4 + 0) * TD_N + j];
      float w1 = W4[(k4 * 4 + 1) * TD_N + j];
      float w2 = W4[(k4 * 4 + 2) * TD_N + j];
      float w3v = W4[(k4 * 4 + 3) * TD_N + j];
#pragma unroll
      for (int r = 0; r < 4; r++) {
        float4 sv = S4[r * 64 + k4];
        z2a[r] += sv.x * w0 + sv.y * w1 + sv.z * w2 + sv.w * w3v;
      }
    }
  }
  for (int r = 0; r < 4; r++) z2a[r] += b4[j];
  __syncthreads();
  for (int r = 0; r < 4; r++) {
    float v = z2a[r], v2 = z2a[r] * z2a[r];
    for (int off = 32; off; off >>= 1) { v += __shfl_down(v, off); v2 += __shfl_down(v2, off); }
    if (lane == 0) { red[r][w][0] = v; red[r][w][1] = v2; }
  }
  __syncthreads();
  for (int r = 0; r < 4; r++) {
    float sm = red[r][0][0] + red[r][1][0] + red[r][2][0] + red[r][3][0];
    float sq = red[r][0][1] + red[r][1][1] + red[r][2][1] + red[r][3][1];
    float mean = sm * (1.0f / TD_N);
    float var = sq * (1.0f / TD_N) - mean * mean;
    float rs = 1.0f / sqrtf(var + 1e-5f);
    float val = (z2a[r] - mean) * rs * g4[j] + bt4[j];
    out[(size_t)(r0 + r) * TD_N + j] = tanhf(val);
  }
}

extern "C" void kernel_launch(void* const* d_in, const int* in_sizes, int n_in,
                              void* d_out, int out_size, void* d_ws, size_t ws_size,
                              hipStream_t stream) {
  const float* obs = (const float*)d_in[0];
  const unsigned char* C = (const unsigned char*)d_in[1];
  const float* W1 = (const float*)d_in[2];  const float* b1 = (const float*)d_in[3];
  const float* g1 = (const float*)d_in[4];  const float* bt1 = (const float*)d_in[5];
  const float* W2 = (const float*)d_in[6];  const float* b2 = (const float*)d_in[7];
  const float* g2 = (const float*)d_in[8];  const float* bt2 = (const float*)d_in[9];
  const float* aW1 = (const float*)d_in[10]; const float* ab1 = (const float*)d_in[11];
  const float* aW2 = (const float*)d_in[12]; const float* ab2 = (const float*)d_in[13];
  const float* aW3 = (const float*)d_in[14]; const float* ab3 = (const float*)d_in[15];
  const float* Wih_f = (const float*)d_in[16]; const float* Whh_f = (const float*)d_in[17];
  const float* bih_f = (const float*)d_in[18]; const float* bhh_f = (const float*)d_in[19];
  const float* Wih_r = (const float*)d_in[20]; const float* Whh_r = (const float*)d_in[21];
  const float* bih_r = (const float*)d_in[22]; const float* bhh_r = (const float*)d_in[23];
  const float* W3 = (const float*)d_in[24]; const float* b3 = (const float*)d_in[25];
  const float* g3 = (const float*)d_in[26]; const float* bt3 = (const float*)d_in[27];
  const float* W4 = (const float*)d_in[28]; const float* b4 = (const float*)d_in[29];
  const float* g4 = (const float*)d_in[30]; const float* bt4 = (const float*)d_in[31];
  float* out = (float*)d_out;

  // Workspace layout (float offsets). t_buf overlaps thB (dead before k_scan).
  float* ws = (float*)d_ws;
  float* Wih4f = ws;                  // 131072
  float* Wih4r = ws + 131072;         // 131072
  float* Whh4f = ws + 262144;         // 65536
  float* Whh4r = ws + 327680;         // 65536
  float* bsumf = ws + 393216;         // 512
  float* bsumr = ws + 393728;         // 512
  float* thB   = ws + 394240;         // 262144 (parity-1 thoughts buffer)
  float* t_buf = ws + 394240;         // overlap: used only before k_prep/k_scan
  int* ibase   = (int*)(ws + 656384);
  int* membi   = ibase;               // 16384
  int* reqi    = ibase + 16384;       // 16384
  int* isin    = ibase + 32768;       // 1024
  int* flag    = ibase + 33792;       // 64
  int* fin     = ibase + 33856;       // 1024
  int* lstart  = ibase + 34880;       // 1027 (pad to 1088)
  int* llist   = ibase + 35968;       // 1024
  int* bar     = ibase + 36992;       // 64
  size_t need = (size_t)(656384 + 37056 + 64) * 4;  // ~2.77 MB
  if (ws_size < need) return;  // diagnosable absmax-fail instead of a fault

  (void)in_sizes; (void)n_in; (void)out_size;

  float* thA = out;  // parity-0 thoughts buffer aliases d_out

  k_cdet<<<1, 64, 0, stream>>>(C, flag);
  k_actor1a<<<256, 256, 0, stream>>>(obs, W1, b1, g1, bt1, t_buf);
  k_actor1b<<<256, 256, 0, stream>>>(t_buf, W2, b2, g2, bt2, thA);
  k_att<<<256, 256, 0, stream>>>(thA, aW1, ab1, aW2, ab2, aW3, ab3, isin);
  k_memb<<<1024, 64, 0, stream>>>(C, flag, membi);
  k_req<<<1024, 256, 0, stream>>>(C, flag, membi, isin, reqi);
  k_prep<<<512, 256, 0, stream>>>(Wih_f, Wih_r, Whh_f, Whh_r, bih_f, bhh_f, bih_r, bhh_r,
                                  Wih4f, Wih4r, Whh4f, Whh4r, bsumf, bsumr, bar);
  k_lvl<<<1, 64, 0, stream>>>(isin, membi, fin, lstart, llist);
  k_scan<<<NWGC, 512, 0, stream>>>(thA, thB, lstart, llist, membi, reqi, bar,
                                   Wih4f, Wih4r, Whh4f, Whh4r, bsumf, bsumr);
  k_actor2<<<256, 256, 0, stream>>>(thA, thB, fin, W3, b3, g3, bt3, W4, b4, g4, bt4, out);
}